// Round 19
// baseline (317.182 us; speedup 1.0000x reference)
//
#include <hip/hip_runtime.h>

#define N_NODES 100000
#define N_EDGES 1600000
#define F_IN 17
#define H 128
#define K_TYPES 6
#define MD 12
#define OUT_F 150
#define EPSL 1e-5f

#define SCAN_BLOCKS 391  // ceil(100000/256)
#define HEAD_BX 391      // heads grid.x; tiles = 3125, grid-stride
#define NBUCK 196        // ceil(100000/512)
#define BCAP 10240       // fixed bucket capacity (mean 8192, sigma~90)

#define LDH 136   // LDS row stride (bf16) for 128-col tiles
#define LDZ 72    // LDS row stride (bf16) for 64-col tiles
#define LDA2 264  // LDS row stride (bf16) for agg2's 256-col tile

typedef __attribute__((ext_vector_type(8))) short bf16x8;
typedef __attribute__((ext_vector_type(4))) float f32x4;
typedef __attribute__((ext_vector_type(2))) float f32x2;

// XOR-swizzled LDS index (shorts): spreads the fixed-16B-column reads across banks.
// col's bits 0-2 untouched -> 8B/16B alignment preserved; bijective per row.
static __device__ __forceinline__ int swzH(int row, int col) {
    return row * LDH + (col ^ ((row & 7) << 3));
}
static __device__ __forceinline__ int swzZ(int row, int col) {
    return row * LDZ + (col ^ ((row & 7) << 3));
}

// pack two f32 -> two bf16 (RNE) in one HW instruction
static __device__ __forceinline__ unsigned pk2(float a, float b) {
    unsigned r;
    asm volatile("v_cvt_pk_bf16_f32 %0, %1, %2" : "=v"(r) : "v"(a), "v"(b));
    return r;
}

static __device__ __forceinline__ short f2bf(float f) {
    return (short)(pk2(f, 0.f) & 0xFFFFu);
}

// fast sigmoid
static __device__ __forceinline__ float fsig(float x) {
    float e = __builtin_amdgcn_exp2f(-1.44269504f * x);
    return __builtin_amdgcn_rcpf(1.f + e);
}

// unpack int2 = 8 fp8(e4m3) via HW cvt and accumulate into acc[0..7]
static __device__ __forceinline__ void accf8(float* a, int2 u) {
    f32x2 p0 = __builtin_amdgcn_cvt_pk_f32_fp8(u.x, false);
    f32x2 p1 = __builtin_amdgcn_cvt_pk_f32_fp8(u.x, true);
    f32x2 p2 = __builtin_amdgcn_cvt_pk_f32_fp8(u.y, false);
    f32x2 p3 = __builtin_amdgcn_cvt_pk_f32_fp8(u.y, true);
    a[0] += p0.x; a[1] += p0.y; a[2] += p1.x; a[3] += p1.y;
    a[4] += p2.x; a[5] += p2.y; a[6] += p3.x; a[7] += p3.y;
}

// ---------- bucket scatter: fixed-capacity regions, one pass over ei ----------
__global__ __launch_bounds__(256) void k_bucket(const int* __restrict__ ei,
                                                int* __restrict__ bcur,
                                                int2* __restrict__ bucketed) {
    __shared__ int lcnt[256];
    __shared__ int lbase[256];
    int t = threadIdx.x;
    lcnt[t] = 0;
    __syncthreads();
    int base = blockIdx.x * 4096;
    int ss[16], dd[16], lr[16], bb[16];
#pragma unroll
    for (int i = 0; i < 16; ++i) {
        int e = base + i * 256 + t;
        bool act = e < N_EDGES;
        ss[i] = act ? ei[e] : 0;
        dd[i] = act ? ei[N_EDGES + e] : 0;
        bb[i] = dd[i] >> 9;
        lr[i] = act ? atomicAdd(&lcnt[bb[i]], 1) : 0;
    }
    __syncthreads();
    if (lcnt[t] > 0) lbase[t] = atomicAdd(&bcur[t], lcnt[t]);
    __syncthreads();
#pragma unroll
    for (int i = 0; i < 16; ++i) {
        int e = base + i * 256 + t;
        if (e < N_EDGES) {
            int2 v; v.x = ss[i]; v.y = dd[i];
            bucketed[(size_t)bb[i] * BCAP + lbase[bb[i]] + lr[i]] = v;
        }
    }
}

// ---------- exact per-dst histogram (1 block per bucket) ----------
__global__ __launch_bounds__(256) void k_hist2(const int2* __restrict__ bucketed,
                                               const int* __restrict__ bsize,
                                               int* __restrict__ cnt) {
    __shared__ int h[512];
    int t = threadIdx.x;
    h[t] = 0; h[t + 256] = 0;
    __syncthreads();
    int b = blockIdx.x;
    int s0 = b * BCAP;
    int s1 = s0 + bsize[b];
    for (int e = s0 + t; e < s1; e += 256)
        atomicAdd(&h[bucketed[e].y & 511], 1);
    __syncthreads();
    int base = b << 9;
#pragma unroll
    for (int q = 0; q < 2; ++q) {
        int j = t + q * 256;
        int idx = base + j;
        if (idx < N_NODES) cnt[idx] = h[j];
    }
}

// ---------- CSR scans ----------
__global__ __launch_bounds__(256) void k_scan1(const int* __restrict__ cnt,
                                               int* __restrict__ rowstart,
                                               int* __restrict__ blocksums) {
    __shared__ int s[256];
    int tid = threadIdx.x;
    int i = blockIdx.x * 256 + tid;
    int v = (i < N_NODES) ? cnt[i] : 0;
    s[tid] = v;
    __syncthreads();
    for (int off = 1; off < 256; off <<= 1) {
        int t = (tid >= off) ? s[tid - off] : 0;
        __syncthreads();
        s[tid] += t;
        __syncthreads();
    }
    if (i < N_NODES) rowstart[i] = s[tid] - v;
    if (tid == 255) blocksums[blockIdx.x] = s[255];
}

__global__ __launch_bounds__(512) void k_scan2(int* __restrict__ blocksums) {
    __shared__ int s[512];
    int t = threadIdx.x;
    int v0 = (t < SCAN_BLOCKS) ? blocksums[t] : 0;
    s[t] = v0;
    __syncthreads();
    for (int off = 1; off < 512; off <<= 1) {
        int tv = (t >= off) ? s[t - off] : 0;
        __syncthreads();
        s[t] += tv;
        __syncthreads();
    }
    if (t < SCAN_BLOCKS) blocksums[t] = s[t] - v0;
}

__global__ __launch_bounds__(256) void k_scan3(int* __restrict__ rowstart,
                                               const int* __restrict__ blocksums,
                                               int* __restrict__ cursor) {
    int i = blockIdx.x * 256 + threadIdx.x;
    if (i < N_NODES) {
        int r = rowstart[i] + blocksums[blockIdx.x];
        rowstart[i] = r;
        cursor[i] = r;
    }
}

// ---------- exact CSR fill from fixed-capacity buckets ----------
__global__ __launch_bounds__(256) void k_fill2(const int2* __restrict__ bucketed,
                                               const int* __restrict__ bsize,
                                               int* __restrict__ cursor,
                                               int* __restrict__ sorted_src) {
    int b = blockIdx.x % NBUCK;
    int off = (blockIdx.x / NBUCK) * 256 + threadIdx.x;
    if (off < bsize[b]) {
        int2 ed = bucketed[(size_t)b * BCAP + off];
        int pos = atomicAdd(&cursor[ed.y], 1);
        sorted_src[pos] = ed.x;
    }
}

// ---------- degree sort ----------
__global__ __launch_bounds__(256) void k_deghist(const int* __restrict__ cnt,
                                                 int* __restrict__ dbins) {
    __shared__ int lb[64];
    int t = threadIdx.x;
    if (t < 64) lb[t] = 0;
    __syncthreads();
    int i = blockIdx.x * 256 + t;
    if (i < N_NODES) {
        int d = cnt[i]; if (d > 63) d = 63;
        atomicAdd(&lb[d], 1);
    }
    __syncthreads();
    if (t < 64 && lb[t] > 0) atomicAdd(&dbins[t], lb[t]);
}

__global__ __launch_bounds__(64) void k_degscan(const int* __restrict__ dbins,
                                                int* __restrict__ dcur) {
    __shared__ int s[64];
    int t = threadIdx.x;
    int v = dbins[t];
    s[t] = v;
    __syncthreads();
    for (int off = 1; off < 64; off <<= 1) {
        int tv = (t >= off) ? s[t - off] : 0;
        __syncthreads();
        s[t] += tv;
        __syncthreads();
    }
    dcur[t] = s[t] - v;
}

__global__ __launch_bounds__(256) void k_degscatter(const int* __restrict__ cnt,
                                                    int* __restrict__ dcur,
                                                    int* __restrict__ perm) {
    __shared__ int lb[64];
    __shared__ int lbase[64];
    int t = threadIdx.x;
    if (t < 64) lb[t] = 0;
    __syncthreads();
    int i = blockIdx.x * 256 + t;
    int d = 0, lrank = 0;
    bool act = (i < N_NODES);
    if (act) {
        d = cnt[i]; if (d > 63) d = 63;
        lrank = atomicAdd(&lb[d], 1);
    }
    __syncthreads();
    if (t < 64 && lb[t] > 0) lbase[t] = atomicAdd(&dcur[t], lb[t]);
    __syncthreads();
    if (act) perm[lbase[d] + lrank] = i;
}

// ---------- prep ----------
__global__ __launch_bounds__(256) void k_prep(
    const float* __restrict__ ch_W1, const float* __restrict__ ch_W2,
    const float* __restrict__ ch_W3,
    const float* __restrict__ c1g, const float* __restrict__ c1b,
    const float* __restrict__ c1m, const float* __restrict__ c1v,
    const float* __restrict__ c2g, const float* __restrict__ c2b,
    const float* __restrict__ c2m, const float* __restrict__ c2v,
    const float* __restrict__ cnt_W1, const float* __restrict__ cnt_W2,
    const float* __restrict__ cbg, const float* __restrict__ cbb,
    const float* __restrict__ cbm, const float* __restrict__ cbv,
    const float* __restrict__ ch_b2, const float* __restrict__ ch_b3,
    const float* __restrict__ cnt_b2,
    const float* __restrict__ W2l, const float* __restrict__ W2r,
    short* __restrict__ W1t, short* __restrict__ W2ft, short* __restrict__ W3ft,
    short* __restrict__ cntW1t, short* __restrict__ cntW2ft,
    short* __restrict__ W2t,
    float* __restrict__ b2f, float* __restrict__ b3f, float* __restrict__ cntb2f) {
    int i = blockIdx.x * 256 + threadIdx.x;
    if (i < 98304) {
        int k = i >> 14, rem = i & 16383, o = rem >> 7, d = rem & 127;
        W1t[i] = f2bf(ch_W1[(k << 14) + (d << 7) + o]);
    } else if ((i -= 98304) < 49152) {
        int k = i >> 13, rem = i & 8191, o = rem >> 7, d = rem & 127;
        int ci = (k << 7) + d;
        float A1 = c1g[ci] * rsqrtf(c1v[ci] + EPSL);
        W2ft[i] = f2bf(ch_W2[(k << 13) + (d << 6) + o] * A1);
    } else if ((i -= 49152) < 12288) {
        int k = i >> 11, rem = i & 2047, o = rem >> 6, d = rem & 63;
        float val = 0.f;
        if (o < 24) {
            int ci = (k << 6) + d;
            float A2 = c2g[ci] * rsqrtf(c2v[ci] + EPSL);
            val = ch_W3[k * 1536 + d * 24 + o] * A2;
        }
        W3ft[i] = f2bf(val);
    } else if ((i -= 12288) < 8192) {
        int o = i >> 7, d = i & 127;
        cntW1t[i] = f2bf(cnt_W1[(d << 6) + o]);
    } else if ((i -= 8192) < 1024) {
        int o = i >> 6, d = i & 63;
        float val = 0.f;
        if (o < 6) val = cnt_W2[d * 6 + o] * (cbg[d] * rsqrtf(cbv[d] + EPSL));
        cntW2ft[i] = f2bf(val);
    } else if ((i -= 1024) < 384) {
        int k = i >> 6, o = i & 63;
        float s = ch_b2[i];
        for (int d = 0; d < 128; ++d) {
            int ci = (k << 7) + d;
            float A1 = c1g[ci] * rsqrtf(c1v[ci] + EPSL);
            float B1 = c1b[ci] - c1m[ci] * A1;
            s += B1 * ch_W2[(k << 13) + (d << 6) + o];
        }
        b2f[i] = s;
    } else if ((i -= 384) < 144) {
        int k = i / 24, o = i - k * 24;
        float s = ch_b3[i];
        for (int d = 0; d < 64; ++d) {
            int ci = (k << 6) + d;
            float A2 = c2g[ci] * rsqrtf(c2v[ci] + EPSL);
            float B2 = c2b[ci] - c2m[ci] * A2;
            s += B2 * ch_W3[k * 1536 + d * 24 + o];
        }
        b3f[i] = s;
    } else if ((i -= 144) < 6) {
        float s = cnt_b2[i];
        for (int d = 0; d < 64; ++d) {
            float Ac = cbg[d] * rsqrtf(cbv[d] + EPSL);
            float Bc = cbb[d] - cbm[d] * Ac;
            s += Bc * cnt_W2[d * 6 + i];
        }
        cntb2f[i] = s;
    } else if ((i -= 6) < 32768) {
        int o = i >> 8, k = i & 255;
        float val = (k < 128) ? W2l[k * 128 + o] : W2r[(k - 128) * 128 + o];
        W2t[i] = f2bf(val);
    }
}

// ---------- fused agg1 + layer1 ----------
__global__ __launch_bounds__(256) void k_agg1_layer1(
    const float* __restrict__ x, const int* __restrict__ rowstart,
    const int* __restrict__ cnt, const int* __restrict__ sorted_src,
    const int* __restrict__ perm,
    const float* __restrict__ W1l, const float* __restrict__ W1r,
    const float* __restrict__ b1,
    const float* __restrict__ g, const float* __restrict__ bb,
    const float* __restrict__ m, const float* __restrict__ v,
    short* __restrict__ h1b, unsigned char* __restrict__ h1f8) {
    __shared__ float as[16][F_IN], xs4[16][F_IN];
    __shared__ int nid[16];
    int t = threadIdx.x;
    int wave = t >> 6, lane = t & 63;
    int q4 = lane >> 4, li = lane & 15;
    int r = wave * 4 + q4;
    int bid = gridDim.x - 1 - blockIdx.x;
    int n = perm[bid * 16 + r];
    if (li == 0) nid[r] = n;
    int rs = rowstart[n];
    int d = cnt[n];

    float a0 = 0.f, a16 = 0.f;
    int j = 0;
    for (; j + 8 <= d; j += 8) {
        int s0 = sorted_src[rs + j], s1 = sorted_src[rs + j + 1];
        int s2 = sorted_src[rs + j + 2], s3 = sorted_src[rs + j + 3];
        int s4 = sorted_src[rs + j + 4], s5 = sorted_src[rs + j + 5];
        int s6 = sorted_src[rs + j + 6], s7 = sorted_src[rs + j + 7];
        float v0 = x[(size_t)s0 * F_IN + li];
        float v1 = x[(size_t)s1 * F_IN + li];
        float v2 = x[(size_t)s2 * F_IN + li];
        float v3 = x[(size_t)s3 * F_IN + li];
        float v4 = x[(size_t)s4 * F_IN + li];
        float v5 = x[(size_t)s5 * F_IN + li];
        float v6 = x[(size_t)s6 * F_IN + li];
        float v7 = x[(size_t)s7 * F_IN + li];
        a0 += ((v0 + v1) + (v2 + v3)) + ((v4 + v5) + (v6 + v7));
        if (li == 0) {
            a16 += ((x[(size_t)s0 * F_IN + 16] + x[(size_t)s1 * F_IN + 16]) +
                    (x[(size_t)s2 * F_IN + 16] + x[(size_t)s3 * F_IN + 16])) +
                   ((x[(size_t)s4 * F_IN + 16] + x[(size_t)s5 * F_IN + 16]) +
                    (x[(size_t)s6 * F_IN + 16] + x[(size_t)s7 * F_IN + 16]));
        }
    }
    for (; j < d; ++j) {
        int s0 = sorted_src[rs + j];
        a0 += x[(size_t)s0 * F_IN + li];
        if (li == 0) a16 += x[(size_t)s0 * F_IN + 16];
    }
    float inv = 1.0f / fmaxf((float)d, 1.0f);
    as[r][li] = a0 * inv;
    xs4[r][li] = x[(size_t)n * F_IN + li];
    if (li == 0) {
        as[r][16] = a16 * inv;
        xs4[r][16] = x[(size_t)n * F_IN + 16];
    }
    __syncthreads();

    int c = t & 127;
    int half = t >> 7;
    float wl[F_IN], wr[F_IN];
#pragma unroll
    for (int i = 0; i < F_IN; ++i) {
        wl[i] = W1l[i * H + c];
        wr[i] = W1r[i * H + c];
    }
    float bi = b1[c];
    float sc = rsqrtf(v[c] + EPSL) * g[c];
    float mm = m[c], be = bb[c];
#pragma unroll
    for (int rep = 0; rep < 8; ++rep) {
        int rr = rep * 2 + half;
        float acc = bi;
#pragma unroll
        for (int i = 0; i < F_IN; ++i)
            acc += as[rr][i] * wl[i] + xs4[rr][i] * wr[i];
        float y = fmaxf((acc - mm) * sc + be, 0.f);
        size_t base = (size_t)nid[rr] * H + c;
        h1b[base] = f2bf(y);
        int p8 = __builtin_amdgcn_cvt_pk_fp8_f32(y, y, 0, false);
        h1f8[base] = (unsigned char)(p8 & 0xFF);
    }
}

// ---------- fused agg2 + layer2: dual-node fp8 gather + MFMA GEMM ----------
__global__ __launch_bounds__(256) void k_agg2_layer2(
    const short* __restrict__ h1b, const unsigned char* __restrict__ h1f8,
    const int* __restrict__ rowstart,
    const int* __restrict__ cnt, const int* __restrict__ sorted_src,
    const int* __restrict__ perm,
    const short* __restrict__ W2t,
    const float* __restrict__ b2,
    const float* __restrict__ g, const float* __restrict__ bb,
    const float* __restrict__ m, const float* __restrict__ v,
    short* __restrict__ hb) {
    __shared__ short xs[32 * LDA2];
    __shared__ int nid[32];
    int t = threadIdx.x;
    int wave = t >> 6, lane = t & 63;
    int q4 = lane >> 4;
    int li = lane & 15;
    int lr = lane & 15, lk = lane >> 4;
    int bid = gridDim.x - 1 - blockIdx.x;
    int n0 = bid * 32;

    {
        int rA = wave * 8 + q4;
        int rB = rA + 4;
        int nA = perm[n0 + rA];
        int nB = perm[n0 + rB];
        if (li == 0) { nid[rA] = nA; nid[rB] = nB; }
        int4 rvA = *(const int4*)&h1b[(size_t)nA * H + li * 8];
        int4 rvB = *(const int4*)&h1b[(size_t)nB * H + li * 8];
        int rsA = rowstart[nA], dA = cnt[nA];
        int rsB = rowstart[nB], dB = cnt[nB];
        float accA[8] = {0.f, 0.f, 0.f, 0.f, 0.f, 0.f, 0.f, 0.f};
        float accB[8] = {0.f, 0.f, 0.f, 0.f, 0.f, 0.f, 0.f, 0.f};
        int dmin = dA < dB ? dA : dB;
        int j = 0;
        for (; j + 4 <= dmin; j += 4) {
            int2 a0 = *(const int2*)&h1f8[(size_t)sorted_src[rsA + j] * H + li * 8];
            int2 a1 = *(const int2*)&h1f8[(size_t)sorted_src[rsA + j + 1] * H + li * 8];
            int2 a2 = *(const int2*)&h1f8[(size_t)sorted_src[rsA + j + 2] * H + li * 8];
            int2 a3 = *(const int2*)&h1f8[(size_t)sorted_src[rsA + j + 3] * H + li * 8];
            int2 b0 = *(const int2*)&h1f8[(size_t)sorted_src[rsB + j] * H + li * 8];
            int2 b1 = *(const int2*)&h1f8[(size_t)sorted_src[rsB + j + 1] * H + li * 8];
            int2 b2_ = *(const int2*)&h1f8[(size_t)sorted_src[rsB + j + 2] * H + li * 8];
            int2 b3 = *(const int2*)&h1f8[(size_t)sorted_src[rsB + j + 3] * H + li * 8];
            accf8(accA, a0); accf8(accA, a1); accf8(accA, a2); accf8(accA, a3);
            accf8(accB, b0); accf8(accB, b1); accf8(accB, b2_); accf8(accB, b3);
        }
        int jA = j, jB = j;
        for (; jA + 4 <= dA; jA += 4) {
            int2 a0 = *(const int2*)&h1f8[(size_t)sorted_src[rsA + jA] * H + li * 8];
            int2 a1 = *(const int2*)&h1f8[(size_t)sorted_src[rsA + jA + 1] * H + li * 8];
            int2 a2 = *(const int2*)&h1f8[(size_t)sorted_src[rsA + jA + 2] * H + li * 8];
            int2 a3 = *(const int2*)&h1f8[(size_t)sorted_src[rsA + jA + 3] * H + li * 8];
            accf8(accA, a0); accf8(accA, a1); accf8(accA, a2); accf8(accA, a3);
        }
        for (; jA < dA; ++jA) {
            int2 a0 = *(const int2*)&h1f8[(size_t)sorted_src[rsA + jA] * H + li * 8];
            accf8(accA, a0);
        }
        for (; jB + 4 <= dB; jB += 4) {
            int2 b0 = *(const int2*)&h1f8[(size_t)sorted_src[rsB + jB] * H + li * 8];
            int2 b1 = *(const int2*)&h1f8[(size_t)sorted_src[rsB + jB + 1] * H + li * 8];
            int2 b2_ = *(const int2*)&h1f8[(size_t)sorted_src[rsB + jB + 2] * H + li * 8];
            int2 b3 = *(const int2*)&h1f8[(size_t)sorted_src[rsB + jB + 3] * H + li * 8];
            accf8(accB, b0); accf8(accB, b1); accf8(accB, b2_); accf8(accB, b3);
        }
        for (; jB < dB; ++jB) {
            int2 b0 = *(const int2*)&h1f8[(size_t)sorted_src[rsB + jB] * H + li * 8];
            accf8(accB, b0);
        }
        float invA = 1.f / fmaxf((float)dA, 1.f);
        float invB = 1.f / fmaxf((float)dB, 1.f);
        unsigned pkA[4], pkB[4];
#pragma unroll
        for (int q = 0; q < 4; ++q) {
            pkA[q] = pk2(accA[2 * q] * invA, accA[2 * q + 1] * invA);
            pkB[q] = pk2(accB[2 * q] * invB, accB[2 * q + 1] * invB);
        }
        *(int4*)&xs[rA * LDA2 + 8 * li] = *(int4*)pkA;
        *(int4*)&xs[rB * LDA2 + 8 * li] = *(int4*)pkB;
        *(int4*)&xs[rA * LDA2 + 128 + 8 * li] = rvA;
        *(int4*)&xs[rB * LDA2 + 128 + 8 * li] = rvB;
    }
    __syncthreads();

    f32x4 acc2[2][2] = {};
    for (int ks = 0; ks < 8; ++ks) {
        bf16x8 b0 = *(const bf16x8*)&W2t[(32 * wave + lr) * 256 + 32 * ks + 8 * lk];
        bf16x8 b1 = *(const bf16x8*)&W2t[(32 * wave + 16 + lr) * 256 + 32 * ks + 8 * lk];
        bf16x8 a0 = *(bf16x8*)&xs[lr * LDA2 + 32 * ks + 8 * lk];
        bf16x8 a1 = *(bf16x8*)&xs[(16 + lr) * LDA2 + 32 * ks + 8 * lk];
        acc2[0][0] = __builtin_amdgcn_mfma_f32_16x16x32_bf16(a0, b0, acc2[0][0], 0, 0, 0);
        acc2[0][1] = __builtin_amdgcn_mfma_f32_16x16x32_bf16(a0, b1, acc2[0][1], 0, 0, 0);
        acc2[1][0] = __builtin_amdgcn_mfma_f32_16x16x32_bf16(a1, b0, acc2[1][0], 0, 0, 0);
        acc2[1][1] = __builtin_amdgcn_mfma_f32_16x16x32_bf16(a1, b1, acc2[1][1], 0, 0, 0);
    }
#pragma unroll
    for (int cc = 0; cc < 2; ++cc) {
        int c = 32 * wave + 16 * cc + lr;
        float bi = b2[c];
        float sc = rsqrtf(v[c] + EPSL) * g[c];
        float mm = m[c], be = bb[c];
#pragma unroll
        for (int rr = 0; rr < 2; ++rr)
#pragma unroll
            for (int j = 0; j < 4; ++j) {
                int row = 16 * rr + 4 * lk + j;
                float y = (acc2[rr][cc][j] + bi - mm) * sc + be;
                hb[(size_t)nid[row] * H + c] = f2bf(fmaxf(y, 0.f));
            }
    }
}

// ---------- heads via MFMA v8: weights-in-registers + XOR-swizzled LDS ----------
__global__ __launch_bounds__(256) void k_heads_mfma(
    const short* __restrict__ hb,
    const float* __restrict__ cntb1, const float* __restrict__ ch_b1,
    const short* __restrict__ W1t, const short* __restrict__ W2ft,
    const short* __restrict__ W3ft, const short* __restrict__ cntW1t,
    const short* __restrict__ cntW2ft,
    const float* __restrict__ b2f, const float* __restrict__ b3f,
    const float* __restrict__ cntb2f,
    float* __restrict__ out) {
    __shared__ short hs[32 * LDH];
    __shared__ short z1[32 * LDH];
    __shared__ short z2[32 * LDZ];

    int t = threadIdx.x;
    int lane = t & 63, w = t >> 6;
    int lr = lane & 15, lk = lane >> 4;
    int rh = w >> 1, ch = w & 1;
    int bx = blockIdx.x, by = blockIdx.y;

    if (by < K_TYPES) {
        int k = by;
        const short* W1k = W1t + k * 16384;
        const short* W2k = W2ft + k * 8192;
        const short* W3k = W3ft + k * 2048;
        bf16x8 A1[2][4], A2[4], A3[2];
#pragma unroll
        for (int cc = 0; cc < 2; ++cc)
#pragma unroll
            for (int ks = 0; ks < 4; ++ks)
                A1[cc][ks] = *(const bf16x8*)&W1k[(32 * w + 16 * cc + lr) * 128 + 32 * ks + 8 * lk];
#pragma unroll
        for (int ks = 0; ks < 4; ++ks)
            A2[ks] = *(const bf16x8*)&W2k[(16 * w + lr) * 128 + 32 * ks + 8 * lk];
#pragma unroll
        for (int ks = 0; ks < 2; ++ks)
            A3[ks] = *(const bf16x8*)&W3k[(16 * ch + lr) * 64 + 32 * ks + 8 * lk];

        for (int tile = bx; tile < 3125; tile += HEAD_BX) {
            int n0 = tile * 32;
#pragma unroll
            for (int it = 0; it < 2; ++it) {
                int idx = (t + it * 256) * 8;
                int r = idx >> 7, c = idx & 127;
                *(int4*)&hs[swzH(r, c)] = *(const int4*)&hb[(size_t)(n0 + r) * 128 + c];
            }
            __syncthreads();
            {
                f32x4 acc[2][2] = {};
#pragma unroll
                for (int ks = 0; ks < 4; ++ks) {
                    bf16x8 b0 = *(bf16x8*)&hs[swzH(lr, 32 * ks + 8 * lk)];
                    bf16x8 b1 = *(bf16x8*)&hs[swzH(16 + lr, 32 * ks + 8 * lk)];
                    acc[0][0] = __builtin_amdgcn_mfma_f32_16x16x32_bf16(A1[0][ks], b0, acc[0][0], 0, 0, 0);
                    acc[0][1] = __builtin_amdgcn_mfma_f32_16x16x32_bf16(A1[0][ks], b1, acc[0][1], 0, 0, 0);
                    acc[1][0] = __builtin_amdgcn_mfma_f32_16x16x32_bf16(A1[1][ks], b0, acc[1][0], 0, 0, 0);
                    acc[1][1] = __builtin_amdgcn_mfma_f32_16x16x32_bf16(A1[1][ks], b1, acc[1][1], 0, 0, 0);
                }
#pragma unroll
                for (int cc = 0; cc < 2; ++cc) {
                    int o0 = 32 * w + 16 * cc + 4 * lk;
                    float4 bi = *(const float4*)&ch_b1[k * 128 + o0];
#pragma unroll
                    for (int nt = 0; nt < 2; ++nt) {
                        int node = nt * 16 + lr;
                        int2 pk;
                        pk.x = pk2(fmaxf(acc[cc][nt][0] + bi.x, 0.f), fmaxf(acc[cc][nt][1] + bi.y, 0.f));
                        pk.y = pk2(fmaxf(acc[cc][nt][2] + bi.z, 0.f), fmaxf(acc[cc][nt][3] + bi.w, 0.f));
                        *(int2*)&z1[swzH(node, o0)] = pk;
                    }
                }
            }
            __syncthreads();
            {
                f32x4 acc[2] = {};
#pragma unroll
                for (int ks = 0; ks < 4; ++ks) {
                    bf16x8 b0 = *(bf16x8*)&z1[swzH(lr, 32 * ks + 8 * lk)];
                    bf16x8 b1 = *(bf16x8*)&z1[swzH(16 + lr, 32 * ks + 8 * lk)];
                    acc[0] = __builtin_amdgcn_mfma_f32_16x16x32_bf16(A2[ks], b0, acc[0], 0, 0, 0);
                    acc[1] = __builtin_amdgcn_mfma_f32_16x16x32_bf16(A2[ks], b1, acc[1], 0, 0, 0);
                }
                int o0 = 16 * w + 4 * lk;
                float4 bi = *(const float4*)&b2f[k * 64 + o0];
#pragma unroll
                for (int nt = 0; nt < 2; ++nt) {
                    int node = nt * 16 + lr;
                    int2 pk;
                    pk.x = pk2(fmaxf(acc[nt][0] + bi.x, 0.f), fmaxf(acc[nt][1] + bi.y, 0.f));
                    pk.y = pk2(fmaxf(acc[nt][2] + bi.z, 0.f), fmaxf(acc[nt][3] + bi.w, 0.f));
                    *(int2*)&z2[swzZ(node, o0)] = pk;
                }
            }
            __syncthreads();
            {
                f32x4 acc = {};
#pragma unroll
                for (int ks = 0; ks < 2; ++ks) {
                    bf16x8 b = *(bf16x8*)&z2[swzZ(16 * rh + lr, 32 * ks + 8 * lk)];
                    acc = __builtin_amdgcn_mfma_f32_16x16x32_bf16(A3[ks], b, acc, 0, 0, 0);
                }
                int o0 = 16 * ch + 4 * lk;
                if (o0 < 24) {
                    int n = n0 + 16 * rh + lr;
                    float b0 = b3f[k * 24 + o0], b1 = b3f[k * 24 + o0 + 1];
                    float b2v = b3f[k * 24 + o0 + 2], b3v = b3f[k * 24 + o0 + 3];
                    float2 s0, s1;
                    s0.x = fsig(acc[0] + b0);
                    s0.y = fsig(acc[1] + b1);
                    s1.x = fsig(acc[2] + b2v);
                    s1.y = fsig(acc[3] + b3v);
                    size_t base = (size_t)n * OUT_F + 6 + 24 * k + o0;
                    *(float2*)&out[base] = s0;
                    *(float2*)&out[base + 2] = s1;
                }
            }
        }
    } else {
        bf16x8 C1[4], C2[2];
#pragma unroll
        for (int ks = 0; ks < 4; ++ks)
            C1[ks] = *(const bf16x8*)&cntW1t[(16 * w + lr) * 128 + 32 * ks + 8 * lk];
#pragma unroll
        for (int ks = 0; ks < 2; ++ks)
            C2[ks] = *(const bf16x8*)&cntW2ft[lr * 64 + 32 * ks + 8 * lk];

        for (int tile = bx; tile < 3125; tile += HEAD_BX) {
            int n0 = tile * 32;
#pragma unroll
            for (int it = 0; it < 2; ++it) {
                int idx = (t + it * 256) * 8;
                int r = idx >> 7, c = idx & 127;
                *(int4*)&hs[swzH(r, c)] = *(const int4*)&hb[(size_t)(n0 + r) * 128 + c];
            }
            __syncthreads();
            {
                f32x4 acc[2] = {};
#pragma unroll
                for (int ks = 0; ks < 4; ++ks) {
                    bf16x8 b0 = *(bf16x8*)&hs[swzH(lr, 32 * ks + 8 * lk)];
                    bf16x8 b1 = *(bf16x8*)&hs[swzH(16 + lr, 32 * ks + 8 * lk)];
                    acc[0] = __builtin_amdgcn_mfma_f32_16x16x32_bf16(C1[ks], b0, acc[0], 0, 0, 0);
                    acc[1] = __builtin_amdgcn_mfma_f32_16x16x32_bf16(C1[ks], b1, acc[1], 0, 0, 0);
                }
                int o0 = 16 * w + 4 * lk;
                float4 bi = *(const float4*)&cntb1[o0];
#pragma unroll
                for (int nt = 0; nt < 2; ++nt) {
                    int node = nt * 16 + lr;
                    int2 pk;
                    pk.x = pk2(fmaxf(acc[nt][0] + bi.x, 0.f), fmaxf(acc[nt][1] + bi.y, 0.f));
                    pk.y = pk2(fmaxf(acc[nt][2] + bi.z, 0.f), fmaxf(acc[nt][3] + bi.w, 0.f));
                    *(int2*)&z2[swzZ(node, o0)] = pk;
                }
            }
            __syncthreads();
            if (w < 2) {
                f32x4 acc = {};
#pragma unroll
                for (int ks = 0; ks < 2; ++ks) {
                    bf16x8 b = *(bf16x8*)&z2[swzZ(16 * w + lr, 32 * ks + 8 * lk)];
                    acc = __builtin_amdgcn_mfma_f32_16x16x32_bf16(C2[ks], b, acc, 0, 0, 0);
                }
                int n = n0 + 16 * w + lr;
#pragma unroll
                for (int j = 0; j < 4; ++j) {
                    int o = 4 * lk + j;
                    if (o < 6) out[(size_t)n * OUT_F + o] = acc[j] + cntb2f[o];
                }
            }
            __syncthreads();
        }
    }
}

extern "C" void kernel_launch(void* const* d_in, const int* in_sizes, int n_in,
                              void* d_out, int out_size, void* d_ws, size_t ws_size,
                              hipStream_t stream) {
    const float* x = (const float*)d_in[0];
    const int* ei = (const int*)d_in[1];
    const float* W1l = (const float*)d_in[2];
    const float* W1r = (const float*)d_in[3];
    const float* b1 = (const float*)d_in[4];
    const float* bn1_g = (const float*)d_in[5];
    const float* bn1_b = (const float*)d_in[6];
    const float* bn1_m = (const float*)d_in[7];
    const float* bn1_v = (const float*)d_in[8];
    const float* W2l = (const float*)d_in[9];
    const float* W2r = (const float*)d_in[10];
    const float* b2 = (const float*)d_in[11];
    const float* bn2_g = (const float*)d_in[12];
    const float* bn2_b = (const float*)d_in[13];
    const float* bn2_m = (const float*)d_in[14];
    const float* bn2_v = (const float*)d_in[15];
    const float* cnt_W1 = (const float*)d_in[16];
    const float* cnt_b1 = (const float*)d_in[17];
    const float* cnt_bn_g = (const float*)d_in[18];
    const float* cnt_bn_b = (const float*)d_in[19];
    const float* cnt_bn_m = (const float*)d_in[20];
    const float* cnt_bn_v = (const float*)d_in[21];
    const float* cnt_W2 = (const float*)d_in[22];
    const float* cnt_b2 = (const float*)d_in[23];
    const float* ch_W1 = (const float*)d_in[24];
    const float* ch_b1 = (const float*)d_in[25];
    const float* ch_bn1_g = (const float*)d_in[26];
    const float* ch_bn1_b = (const float*)d_in[27];
    const float* ch_bn1_m = (const float*)d_in[28];
    const float* ch_bn1_v = (const float*)d_in[29];
    const float* ch_W2 = (const float*)d_in[30];
    const float* ch_b2 = (const float*)d_in[31];
    const float* ch_bn2_g = (const float*)d_in[32];
    const float* ch_bn2_b = (const float*)d_in[33];
    const float* ch_bn2_m = (const float*)d_in[34];
    const float* ch_bn2_v = (const float*)d_in[35];
    const float* ch_W3 = (const float*)d_in[36];
    const float* ch_b3 = (const float*)d_in[37];

    float* out = (float*)d_out;

    int* cnt = (int*)d_ws;
    int* dbins = cnt + N_NODES;
    int* bcur = dbins + 64;
    int* dcur = bcur + 256;
    int* rowstart = dcur + 64;
    int* cursor = rowstart + N_NODES;
    int* blocksums = cursor + N_NODES;
    int* perm = blocksums + 512;
    int* sorted_src = perm + N_NODES;
    int2* bucketed = (int2*)(sorted_src + N_EDGES);
    unsigned char* h1f8 = (unsigned char*)bucketed;  // aliased; bucketed dead after fill2
    short* h1b = (short*)(bucketed + (size_t)NBUCK * BCAP);
    short* hb = h1b + (size_t)N_NODES * H;
    short* W1t = hb + (size_t)N_NODES * H;
    short* W2ft = W1t + 98304;
    short* W3ft = W2ft + 49152;
    short* cntW1t = W3ft + 12288;
    short* cntW2ft = cntW1t + 8192;
    short* W2t = cntW2ft + 1024;
    float* b2f = (float*)(W2t + 32768);
    float* b3f = b2f + 384;
    float* cntb2f = b3f + 144;

    hipMemsetAsync(dbins, 0, (64 + 256) * sizeof(int), stream);

    k_prep<<<791, 256, 0, stream>>>(ch_W1, ch_W2, ch_W3,
                                    ch_bn1_g, ch_bn1_b, ch_bn1_m, ch_bn1_v,
                                    ch_bn2_g, ch_bn2_b, ch_bn2_m, ch_bn2_v,
                                    cnt_W1, cnt_W2,
                                    cnt_bn_g, cnt_bn_b, cnt_bn_m, cnt_bn_v,
                                    ch_b2, ch_b3, cnt_b2, W2l, W2r,
                                    W1t, W2ft, W3ft, cntW1t, cntW2ft, W2t,
                                    b2f, b3f, cntb2f);

    k_bucket<<<391, 256, 0, stream>>>(ei, bcur, bucketed);
    k_hist2<<<NBUCK, 256, 0, stream>>>(bucketed, bcur, cnt);
    k_scan1<<<SCAN_BLOCKS, 256, 0, stream>>>(cnt, rowstart, blocksums);
    k_scan2<<<1, 512, 0, stream>>>(blocksums);
    k_scan3<<<SCAN_BLOCKS, 256, 0, stream>>>(rowstart, blocksums, cursor);
    k_fill2<<<NBUCK * 40, 256, 0, stream>>>(bucketed, bcur, cursor, sorted_src);

    k_deghist<<<SCAN_BLOCKS, 256, 0, stream>>>(cnt, dbins);
    k_degscan<<<1, 64, 0, stream>>>(dbins, dcur);
    k_degscatter<<<SCAN_BLOCKS, 256, 0, stream>>>(cnt, dcur, perm);

    k_agg1_layer1<<<N_NODES / 16, 256, 0, stream>>>(x, rowstart, cnt, sorted_src, perm,
                                                    W1l, W1r, b1,
                                                    bn1_g, bn1_b, bn1_m, bn1_v, h1b, h1f8);
    k_agg2_layer2<<<N_NODES / 32, 256, 0, stream>>>(h1b, h1f8, rowstart, cnt, sorted_src, perm,
                                                    W2t, b2,
                                                    bn2_g, bn2_b, bn2_m, bn2_v, hb);
    k_heads_mfma<<<dim3(HEAD_BX, 7), 256, 0, stream>>>(
        hb, cnt_b1, ch_b1, W1t, W2ft, W3ft, cntW1t, cntW2ft,
        b2f, b3f, cntb2f, out);
}

// Round 20
// 283.186 us; speedup vs baseline: 1.1200x; 1.1200x over previous
//
#include <hip/hip_runtime.h>

#define N_NODES 100000
#define N_EDGES 1600000
#define F_IN 17
#define H 128
#define K_TYPES 6
#define MD 12
#define OUT_F 150
#define EPSL 1e-5f

#define SCAN_BLOCKS 391  // ceil(100000/256)
#define HEAD_BX 391      // heads grid.x; tiles = 3125, grid-stride
#define NBUCK 196        // ceil(100000/512)
#define BCAP 10240       // fixed bucket capacity (mean 8192, sigma~90)

#define LDH 136   // LDS row stride (bf16) for 128-col tiles
#define LDZ 72    // LDS row stride (bf16) for 64-col tiles
#define LDA2 264  // LDS row stride (bf16) for agg2's 256-col tile

typedef __attribute__((ext_vector_type(8))) short bf16x8;
typedef __attribute__((ext_vector_type(4))) float f32x4;
typedef __attribute__((ext_vector_type(2))) float f32x2;

// pack two f32 -> two bf16 (RNE) in one HW instruction
static __device__ __forceinline__ unsigned pk2(float a, float b) {
    unsigned r;
    asm volatile("v_cvt_pk_bf16_f32 %0, %1, %2" : "=v"(r) : "v"(a), "v"(b));
    return r;
}

static __device__ __forceinline__ short f2bf(float f) {
    return (short)(pk2(f, 0.f) & 0xFFFFu);
}

// fast sigmoid
static __device__ __forceinline__ float fsig(float x) {
    float e = __builtin_amdgcn_exp2f(-1.44269504f * x);
    return __builtin_amdgcn_rcpf(1.f + e);
}

// unpack int2 = 8 fp8(e4m3) via HW cvt and accumulate into acc[0..7]
static __device__ __forceinline__ void accf8(float* a, int2 u) {
    f32x2 p0 = __builtin_amdgcn_cvt_pk_f32_fp8(u.x, false);
    f32x2 p1 = __builtin_amdgcn_cvt_pk_f32_fp8(u.x, true);
    f32x2 p2 = __builtin_amdgcn_cvt_pk_f32_fp8(u.y, false);
    f32x2 p3 = __builtin_amdgcn_cvt_pk_f32_fp8(u.y, true);
    a[0] += p0.x; a[1] += p0.y; a[2] += p1.x; a[3] += p1.y;
    a[4] += p2.x; a[5] += p2.y; a[6] += p3.x; a[7] += p3.y;
}

// ---------- bucket scatter: fixed-capacity regions, one pass over ei ----------
__global__ __launch_bounds__(256) void k_bucket(const int* __restrict__ ei,
                                                int* __restrict__ bcur,
                                                int2* __restrict__ bucketed) {
    __shared__ int lcnt[256];
    __shared__ int lbase[256];
    int t = threadIdx.x;
    lcnt[t] = 0;
    __syncthreads();
    int base = blockIdx.x * 4096;
    int ss[16], dd[16], lr[16], bb[16];
#pragma unroll
    for (int i = 0; i < 16; ++i) {
        int e = base + i * 256 + t;
        bool act = e < N_EDGES;
        ss[i] = act ? ei[e] : 0;
        dd[i] = act ? ei[N_EDGES + e] : 0;
        bb[i] = dd[i] >> 9;
        lr[i] = act ? atomicAdd(&lcnt[bb[i]], 1) : 0;
    }
    __syncthreads();
    if (lcnt[t] > 0) lbase[t] = atomicAdd(&bcur[t], lcnt[t]);
    __syncthreads();
#pragma unroll
    for (int i = 0; i < 16; ++i) {
        int e = base + i * 256 + t;
        if (e < N_EDGES) {
            int2 v; v.x = ss[i]; v.y = dd[i];
            bucketed[(size_t)bb[i] * BCAP + lbase[bb[i]] + lr[i]] = v;
        }
    }
}

// ---------- exact per-dst histogram (1 block per bucket) ----------
__global__ __launch_bounds__(256) void k_hist2(const int2* __restrict__ bucketed,
                                               const int* __restrict__ bsize,
                                               int* __restrict__ cnt) {
    __shared__ int h[512];
    int t = threadIdx.x;
    h[t] = 0; h[t + 256] = 0;
    __syncthreads();
    int b = blockIdx.x;
    int s0 = b * BCAP;
    int s1 = s0 + bsize[b];
    for (int e = s0 + t; e < s1; e += 256)
        atomicAdd(&h[bucketed[e].y & 511], 1);
    __syncthreads();
    int base = b << 9;
#pragma unroll
    for (int q = 0; q < 2; ++q) {
        int j = t + q * 256;
        int idx = base + j;
        if (idx < N_NODES) cnt[idx] = h[j];
    }
}

// ---------- CSR scans ----------
__global__ __launch_bounds__(256) void k_scan1(const int* __restrict__ cnt,
                                               int* __restrict__ rowstart,
                                               int* __restrict__ blocksums) {
    __shared__ int s[256];
    int tid = threadIdx.x;
    int i = blockIdx.x * 256 + tid;
    int v = (i < N_NODES) ? cnt[i] : 0;
    s[tid] = v;
    __syncthreads();
    for (int off = 1; off < 256; off <<= 1) {
        int t = (tid >= off) ? s[tid - off] : 0;
        __syncthreads();
        s[tid] += t;
        __syncthreads();
    }
    if (i < N_NODES) rowstart[i] = s[tid] - v;
    if (tid == 255) blocksums[blockIdx.x] = s[255];
}

__global__ __launch_bounds__(512) void k_scan2(int* __restrict__ blocksums) {
    __shared__ int s[512];
    int t = threadIdx.x;
    int v0 = (t < SCAN_BLOCKS) ? blocksums[t] : 0;
    s[t] = v0;
    __syncthreads();
    for (int off = 1; off < 512; off <<= 1) {
        int tv = (t >= off) ? s[t - off] : 0;
        __syncthreads();
        s[t] += tv;
        __syncthreads();
    }
    if (t < SCAN_BLOCKS) blocksums[t] = s[t] - v0;
}

__global__ __launch_bounds__(256) void k_scan3(int* __restrict__ rowstart,
                                               const int* __restrict__ blocksums,
                                               int* __restrict__ cursor) {
    int i = blockIdx.x * 256 + threadIdx.x;
    if (i < N_NODES) {
        int r = rowstart[i] + blocksums[blockIdx.x];
        rowstart[i] = r;
        cursor[i] = r;
    }
}

// ---------- exact CSR fill from fixed-capacity buckets ----------
__global__ __launch_bounds__(256) void k_fill2(const int2* __restrict__ bucketed,
                                               const int* __restrict__ bsize,
                                               int* __restrict__ cursor,
                                               int* __restrict__ sorted_src) {
    int b = blockIdx.x % NBUCK;
    int off = (blockIdx.x / NBUCK) * 256 + threadIdx.x;
    if (off < bsize[b]) {
        int2 ed = bucketed[(size_t)b * BCAP + off];
        int pos = atomicAdd(&cursor[ed.y], 1);
        sorted_src[pos] = ed.x;
    }
}

// ---------- degree sort ----------
__global__ __launch_bounds__(256) void k_deghist(const int* __restrict__ cnt,
                                                 int* __restrict__ dbins) {
    __shared__ int lb[64];
    int t = threadIdx.x;
    if (t < 64) lb[t] = 0;
    __syncthreads();
    int i = blockIdx.x * 256 + t;
    if (i < N_NODES) {
        int d = cnt[i]; if (d > 63) d = 63;
        atomicAdd(&lb[d], 1);
    }
    __syncthreads();
    if (t < 64 && lb[t] > 0) atomicAdd(&dbins[t], lb[t]);
}

__global__ __launch_bounds__(64) void k_degscan(const int* __restrict__ dbins,
                                                int* __restrict__ dcur) {
    __shared__ int s[64];
    int t = threadIdx.x;
    int v = dbins[t];
    s[t] = v;
    __syncthreads();
    for (int off = 1; off < 64; off <<= 1) {
        int tv = (t >= off) ? s[t - off] : 0;
        __syncthreads();
        s[t] += tv;
        __syncthreads();
    }
    dcur[t] = s[t] - v;
}

__global__ __launch_bounds__(256) void k_degscatter(const int* __restrict__ cnt,
                                                    int* __restrict__ dcur,
                                                    int* __restrict__ perm) {
    __shared__ int lb[64];
    __shared__ int lbase[64];
    int t = threadIdx.x;
    if (t < 64) lb[t] = 0;
    __syncthreads();
    int i = blockIdx.x * 256 + t;
    int d = 0, lrank = 0;
    bool act = (i < N_NODES);
    if (act) {
        d = cnt[i]; if (d > 63) d = 63;
        lrank = atomicAdd(&lb[d], 1);
    }
    __syncthreads();
    if (t < 64 && lb[t] > 0) lbase[t] = atomicAdd(&dcur[t], lb[t]);
    __syncthreads();
    if (act) perm[lbase[d] + lrank] = i;
}

// ---------- prep ----------
__global__ __launch_bounds__(256) void k_prep(
    const float* __restrict__ ch_W1, const float* __restrict__ ch_W2,
    const float* __restrict__ ch_W3,
    const float* __restrict__ c1g, const float* __restrict__ c1b,
    const float* __restrict__ c1m, const float* __restrict__ c1v,
    const float* __restrict__ c2g, const float* __restrict__ c2b,
    const float* __restrict__ c2m, const float* __restrict__ c2v,
    const float* __restrict__ cnt_W1, const float* __restrict__ cnt_W2,
    const float* __restrict__ cbg, const float* __restrict__ cbb,
    const float* __restrict__ cbm, const float* __restrict__ cbv,
    const float* __restrict__ ch_b2, const float* __restrict__ ch_b3,
    const float* __restrict__ cnt_b2,
    const float* __restrict__ W2l, const float* __restrict__ W2r,
    short* __restrict__ W1t, short* __restrict__ W2ft, short* __restrict__ W3ft,
    short* __restrict__ cntW1t, short* __restrict__ cntW2ft,
    short* __restrict__ W2t,
    float* __restrict__ b2f, float* __restrict__ b3f, float* __restrict__ cntb2f) {
    int i = blockIdx.x * 256 + threadIdx.x;
    if (i < 98304) {
        int k = i >> 14, rem = i & 16383, o = rem >> 7, d = rem & 127;
        W1t[i] = f2bf(ch_W1[(k << 14) + (d << 7) + o]);
    } else if ((i -= 98304) < 49152) {
        int k = i >> 13, rem = i & 8191, o = rem >> 7, d = rem & 127;
        int ci = (k << 7) + d;
        float A1 = c1g[ci] * rsqrtf(c1v[ci] + EPSL);
        W2ft[i] = f2bf(ch_W2[(k << 13) + (d << 6) + o] * A1);
    } else if ((i -= 49152) < 12288) {
        int k = i >> 11, rem = i & 2047, o = rem >> 6, d = rem & 63;
        float val = 0.f;
        if (o < 24) {
            int ci = (k << 6) + d;
            float A2 = c2g[ci] * rsqrtf(c2v[ci] + EPSL);
            val = ch_W3[k * 1536 + d * 24 + o] * A2;
        }
        W3ft[i] = f2bf(val);
    } else if ((i -= 12288) < 8192) {
        int o = i >> 7, d = i & 127;
        cntW1t[i] = f2bf(cnt_W1[(d << 6) + o]);
    } else if ((i -= 8192) < 1024) {
        int o = i >> 6, d = i & 63;
        float val = 0.f;
        if (o < 6) val = cnt_W2[d * 6 + o] * (cbg[d] * rsqrtf(cbv[d] + EPSL));
        cntW2ft[i] = f2bf(val);
    } else if ((i -= 1024) < 384) {
        int k = i >> 6, o = i & 63;
        float s = ch_b2[i];
        for (int d = 0; d < 128; ++d) {
            int ci = (k << 7) + d;
            float A1 = c1g[ci] * rsqrtf(c1v[ci] + EPSL);
            float B1 = c1b[ci] - c1m[ci] * A1;
            s += B1 * ch_W2[(k << 13) + (d << 6) + o];
        }
        b2f[i] = s;
    } else if ((i -= 384) < 144) {
        int k = i / 24, o = i - k * 24;
        float s = ch_b3[i];
        for (int d = 0; d < 64; ++d) {
            int ci = (k << 6) + d;
            float A2 = c2g[ci] * rsqrtf(c2v[ci] + EPSL);
            float B2 = c2b[ci] - c2m[ci] * A2;
            s += B2 * ch_W3[k * 1536 + d * 24 + o];
        }
        b3f[i] = s;
    } else if ((i -= 144) < 6) {
        float s = cnt_b2[i];
        for (int d = 0; d < 64; ++d) {
            float Ac = cbg[d] * rsqrtf(cbv[d] + EPSL);
            float Bc = cbb[d] - cbm[d] * Ac;
            s += Bc * cnt_W2[d * 6 + i];
        }
        cntb2f[i] = s;
    } else if ((i -= 6) < 32768) {
        int o = i >> 8, k = i & 255;
        float val = (k < 128) ? W2l[k * 128 + o] : W2r[(k - 128) * 128 + o];
        W2t[i] = f2bf(val);
    }
}

// ---------- fused agg1 + layer1 ----------
__global__ __launch_bounds__(256) void k_agg1_layer1(
    const float* __restrict__ x, const int* __restrict__ rowstart,
    const int* __restrict__ cnt, const int* __restrict__ sorted_src,
    const int* __restrict__ perm,
    const float* __restrict__ W1l, const float* __restrict__ W1r,
    const float* __restrict__ b1,
    const float* __restrict__ g, const float* __restrict__ bb,
    const float* __restrict__ m, const float* __restrict__ v,
    short* __restrict__ h1b, unsigned char* __restrict__ h1f8) {
    __shared__ float as[16][F_IN], xs4[16][F_IN];
    __shared__ int nid[16];
    int t = threadIdx.x;
    int wave = t >> 6, lane = t & 63;
    int q4 = lane >> 4, li = lane & 15;
    int r = wave * 4 + q4;
    int bid = gridDim.x - 1 - blockIdx.x;
    int n = perm[bid * 16 + r];
    if (li == 0) nid[r] = n;
    int rs = rowstart[n];
    int d = cnt[n];

    float a0 = 0.f, a16 = 0.f;
    int j = 0;
    for (; j + 8 <= d; j += 8) {
        int s0 = sorted_src[rs + j], s1 = sorted_src[rs + j + 1];
        int s2 = sorted_src[rs + j + 2], s3 = sorted_src[rs + j + 3];
        int s4 = sorted_src[rs + j + 4], s5 = sorted_src[rs + j + 5];
        int s6 = sorted_src[rs + j + 6], s7 = sorted_src[rs + j + 7];
        float v0 = x[(size_t)s0 * F_IN + li];
        float v1 = x[(size_t)s1 * F_IN + li];
        float v2 = x[(size_t)s2 * F_IN + li];
        float v3 = x[(size_t)s3 * F_IN + li];
        float v4 = x[(size_t)s4 * F_IN + li];
        float v5 = x[(size_t)s5 * F_IN + li];
        float v6 = x[(size_t)s6 * F_IN + li];
        float v7 = x[(size_t)s7 * F_IN + li];
        a0 += ((v0 + v1) + (v2 + v3)) + ((v4 + v5) + (v6 + v7));
        if (li == 0) {
            a16 += ((x[(size_t)s0 * F_IN + 16] + x[(size_t)s1 * F_IN + 16]) +
                    (x[(size_t)s2 * F_IN + 16] + x[(size_t)s3 * F_IN + 16])) +
                   ((x[(size_t)s4 * F_IN + 16] + x[(size_t)s5 * F_IN + 16]) +
                    (x[(size_t)s6 * F_IN + 16] + x[(size_t)s7 * F_IN + 16]));
        }
    }
    for (; j < d; ++j) {
        int s0 = sorted_src[rs + j];
        a0 += x[(size_t)s0 * F_IN + li];
        if (li == 0) a16 += x[(size_t)s0 * F_IN + 16];
    }
    float inv = 1.0f / fmaxf((float)d, 1.0f);
    as[r][li] = a0 * inv;
    xs4[r][li] = x[(size_t)n * F_IN + li];
    if (li == 0) {
        as[r][16] = a16 * inv;
        xs4[r][16] = x[(size_t)n * F_IN + 16];
    }
    __syncthreads();

    int c = t & 127;
    int half = t >> 7;
    float wl[F_IN], wr[F_IN];
#pragma unroll
    for (int i = 0; i < F_IN; ++i) {
        wl[i] = W1l[i * H + c];
        wr[i] = W1r[i * H + c];
    }
    float bi = b1[c];
    float sc = rsqrtf(v[c] + EPSL) * g[c];
    float mm = m[c], be = bb[c];
#pragma unroll
    for (int rep = 0; rep < 8; ++rep) {
        int rr = rep * 2 + half;
        float acc = bi;
#pragma unroll
        for (int i = 0; i < F_IN; ++i)
            acc += as[rr][i] * wl[i] + xs4[rr][i] * wr[i];
        float y = fmaxf((acc - mm) * sc + be, 0.f);
        size_t base = (size_t)nid[rr] * H + c;
        h1b[base] = f2bf(y);
        int p8 = __builtin_amdgcn_cvt_pk_fp8_f32(y, y, 0, false);
        h1f8[base] = (unsigned char)(p8 & 0xFF);
    }
}

// ---------- fused agg2 + layer2: dual-node fp8 gather + MFMA GEMM ----------
__global__ __launch_bounds__(256) void k_agg2_layer2(
    const short* __restrict__ h1b, const unsigned char* __restrict__ h1f8,
    const int* __restrict__ rowstart,
    const int* __restrict__ cnt, const int* __restrict__ sorted_src,
    const int* __restrict__ perm,
    const short* __restrict__ W2t,
    const float* __restrict__ b2,
    const float* __restrict__ g, const float* __restrict__ bb,
    const float* __restrict__ m, const float* __restrict__ v,
    short* __restrict__ hb) {
    __shared__ short xs[32 * LDA2];
    __shared__ int nid[32];
    int t = threadIdx.x;
    int wave = t >> 6, lane = t & 63;
    int q4 = lane >> 4;
    int li = lane & 15;
    int lr = lane & 15, lk = lane >> 4;
    int bid = gridDim.x - 1 - blockIdx.x;
    int n0 = bid * 32;

    {
        int rA = wave * 8 + q4;
        int rB = rA + 4;
        int nA = perm[n0 + rA];
        int nB = perm[n0 + rB];
        if (li == 0) { nid[rA] = nA; nid[rB] = nB; }
        int4 rvA = *(const int4*)&h1b[(size_t)nA * H + li * 8];
        int4 rvB = *(const int4*)&h1b[(size_t)nB * H + li * 8];
        int rsA = rowstart[nA], dA = cnt[nA];
        int rsB = rowstart[nB], dB = cnt[nB];
        float accA[8] = {0.f, 0.f, 0.f, 0.f, 0.f, 0.f, 0.f, 0.f};
        float accB[8] = {0.f, 0.f, 0.f, 0.f, 0.f, 0.f, 0.f, 0.f};
        int dmin = dA < dB ? dA : dB;
        int j = 0;
        for (; j + 4 <= dmin; j += 4) {
            int2 a0 = *(const int2*)&h1f8[(size_t)sorted_src[rsA + j] * H + li * 8];
            int2 a1 = *(const int2*)&h1f8[(size_t)sorted_src[rsA + j + 1] * H + li * 8];
            int2 a2 = *(const int2*)&h1f8[(size_t)sorted_src[rsA + j + 2] * H + li * 8];
            int2 a3 = *(const int2*)&h1f8[(size_t)sorted_src[rsA + j + 3] * H + li * 8];
            int2 b0 = *(const int2*)&h1f8[(size_t)sorted_src[rsB + j] * H + li * 8];
            int2 b1 = *(const int2*)&h1f8[(size_t)sorted_src[rsB + j + 1] * H + li * 8];
            int2 b2_ = *(const int2*)&h1f8[(size_t)sorted_src[rsB + j + 2] * H + li * 8];
            int2 b3 = *(const int2*)&h1f8[(size_t)sorted_src[rsB + j + 3] * H + li * 8];
            accf8(accA, a0); accf8(accA, a1); accf8(accA, a2); accf8(accA, a3);
            accf8(accB, b0); accf8(accB, b1); accf8(accB, b2_); accf8(accB, b3);
        }
        int jA = j, jB = j;
        for (; jA + 4 <= dA; jA += 4) {
            int2 a0 = *(const int2*)&h1f8[(size_t)sorted_src[rsA + jA] * H + li * 8];
            int2 a1 = *(const int2*)&h1f8[(size_t)sorted_src[rsA + jA + 1] * H + li * 8];
            int2 a2 = *(const int2*)&h1f8[(size_t)sorted_src[rsA + jA + 2] * H + li * 8];
            int2 a3 = *(const int2*)&h1f8[(size_t)sorted_src[rsA + jA + 3] * H + li * 8];
            accf8(accA, a0); accf8(accA, a1); accf8(accA, a2); accf8(accA, a3);
        }
        for (; jA < dA; ++jA) {
            int2 a0 = *(const int2*)&h1f8[(size_t)sorted_src[rsA + jA] * H + li * 8];
            accf8(accA, a0);
        }
        for (; jB + 4 <= dB; jB += 4) {
            int2 b0 = *(const int2*)&h1f8[(size_t)sorted_src[rsB + jB] * H + li * 8];
            int2 b1 = *(const int2*)&h1f8[(size_t)sorted_src[rsB + jB + 1] * H + li * 8];
            int2 b2_ = *(const int2*)&h1f8[(size_t)sorted_src[rsB + jB + 2] * H + li * 8];
            int2 b3 = *(const int2*)&h1f8[(size_t)sorted_src[rsB + jB + 3] * H + li * 8];
            accf8(accB, b0); accf8(accB, b1); accf8(accB, b2_); accf8(accB, b3);
        }
        for (; jB < dB; ++jB) {
            int2 b0 = *(const int2*)&h1f8[(size_t)sorted_src[rsB + jB] * H + li * 8];
            accf8(accB, b0);
        }
        float invA = 1.f / fmaxf((float)dA, 1.f);
        float invB = 1.f / fmaxf((float)dB, 1.f);
        unsigned pkA[4], pkB[4];
#pragma unroll
        for (int q = 0; q < 4; ++q) {
            pkA[q] = pk2(accA[2 * q] * invA, accA[2 * q + 1] * invA);
            pkB[q] = pk2(accB[2 * q] * invB, accB[2 * q + 1] * invB);
        }
        *(int4*)&xs[rA * LDA2 + 8 * li] = *(int4*)pkA;
        *(int4*)&xs[rB * LDA2 + 8 * li] = *(int4*)pkB;
        *(int4*)&xs[rA * LDA2 + 128 + 8 * li] = rvA;
        *(int4*)&xs[rB * LDA2 + 128 + 8 * li] = rvB;
    }
    __syncthreads();

    f32x4 acc2[2][2] = {};
    for (int ks = 0; ks < 8; ++ks) {
        bf16x8 b0 = *(const bf16x8*)&W2t[(32 * wave + lr) * 256 + 32 * ks + 8 * lk];
        bf16x8 b1 = *(const bf16x8*)&W2t[(32 * wave + 16 + lr) * 256 + 32 * ks + 8 * lk];
        bf16x8 a0 = *(bf16x8*)&xs[lr * LDA2 + 32 * ks + 8 * lk];
        bf16x8 a1 = *(bf16x8*)&xs[(16 + lr) * LDA2 + 32 * ks + 8 * lk];
        acc2[0][0] = __builtin_amdgcn_mfma_f32_16x16x32_bf16(a0, b0, acc2[0][0], 0, 0, 0);
        acc2[0][1] = __builtin_amdgcn_mfma_f32_16x16x32_bf16(a0, b1, acc2[0][1], 0, 0, 0);
        acc2[1][0] = __builtin_amdgcn_mfma_f32_16x16x32_bf16(a1, b0, acc2[1][0], 0, 0, 0);
        acc2[1][1] = __builtin_amdgcn_mfma_f32_16x16x32_bf16(a1, b1, acc2[1][1], 0, 0, 0);
    }
#pragma unroll
    for (int cc = 0; cc < 2; ++cc) {
        int c = 32 * wave + 16 * cc + lr;
        float bi = b2[c];
        float sc = rsqrtf(v[c] + EPSL) * g[c];
        float mm = m[c], be = bb[c];
#pragma unroll
        for (int rr = 0; rr < 2; ++rr)
#pragma unroll
            for (int j = 0; j < 4; ++j) {
                int row = 16 * rr + 4 * lk + j;
                float y = (acc2[rr][cc][j] + bi - mm) * sc + be;
                hb[(size_t)nid[row] * H + c] = f2bf(fmaxf(y, 0.f));
            }
    }
}

// ---------- heads via MFMA v7: weights-in-registers, grid-stride tiles (round-18 layout) ----------
__global__ __launch_bounds__(256) void k_heads_mfma(
    const short* __restrict__ hb,
    const float* __restrict__ cntb1, const float* __restrict__ ch_b1,
    const short* __restrict__ W1t, const short* __restrict__ W2ft,
    const short* __restrict__ W3ft, const short* __restrict__ cntW1t,
    const short* __restrict__ cntW2ft,
    const float* __restrict__ b2f, const float* __restrict__ b3f,
    const float* __restrict__ cntb2f,
    float* __restrict__ out) {
    __shared__ short hs[32 * LDH];
    __shared__ short z1[32 * LDH];
    __shared__ short z2[32 * LDZ];

    int t = threadIdx.x;
    int lane = t & 63, w = t >> 6;
    int lr = lane & 15, lk = lane >> 4;
    int rh = w >> 1, ch = w & 1;
    int bx = blockIdx.x, by = blockIdx.y;

    if (by < K_TYPES) {
        int k = by;
        const short* W1k = W1t + k * 16384;
        const short* W2k = W2ft + k * 8192;
        const short* W3k = W3ft + k * 2048;
        bf16x8 A1[2][4], A2[4], A3[2];
#pragma unroll
        for (int cc = 0; cc < 2; ++cc)
#pragma unroll
            for (int ks = 0; ks < 4; ++ks)
                A1[cc][ks] = *(const bf16x8*)&W1k[(32 * w + 16 * cc + lr) * 128 + 32 * ks + 8 * lk];
#pragma unroll
        for (int ks = 0; ks < 4; ++ks)
            A2[ks] = *(const bf16x8*)&W2k[(16 * w + lr) * 128 + 32 * ks + 8 * lk];
#pragma unroll
        for (int ks = 0; ks < 2; ++ks)
            A3[ks] = *(const bf16x8*)&W3k[(16 * ch + lr) * 64 + 32 * ks + 8 * lk];

        for (int tile = bx; tile < 3125; tile += HEAD_BX) {
            int n0 = tile * 32;
#pragma unroll
            for (int it = 0; it < 2; ++it) {
                int idx = (t + it * 256) * 8;
                int r = idx >> 7, c = idx & 127;
                *(int4*)&hs[r * LDH + c] = *(const int4*)&hb[(size_t)(n0 + r) * 128 + c];
            }
            __syncthreads();
            {
                f32x4 acc[2][2] = {};
#pragma unroll
                for (int ks = 0; ks < 4; ++ks) {
                    bf16x8 b0 = *(bf16x8*)&hs[lr * LDH + 32 * ks + 8 * lk];
                    bf16x8 b1 = *(bf16x8*)&hs[(16 + lr) * LDH + 32 * ks + 8 * lk];
                    acc[0][0] = __builtin_amdgcn_mfma_f32_16x16x32_bf16(A1[0][ks], b0, acc[0][0], 0, 0, 0);
                    acc[0][1] = __builtin_amdgcn_mfma_f32_16x16x32_bf16(A1[0][ks], b1, acc[0][1], 0, 0, 0);
                    acc[1][0] = __builtin_amdgcn_mfma_f32_16x16x32_bf16(A1[1][ks], b0, acc[1][0], 0, 0, 0);
                    acc[1][1] = __builtin_amdgcn_mfma_f32_16x16x32_bf16(A1[1][ks], b1, acc[1][1], 0, 0, 0);
                }
#pragma unroll
                for (int cc = 0; cc < 2; ++cc) {
                    int o0 = 32 * w + 16 * cc + 4 * lk;
                    float4 bi = *(const float4*)&ch_b1[k * 128 + o0];
#pragma unroll
                    for (int nt = 0; nt < 2; ++nt) {
                        int node = nt * 16 + lr;
                        int2 pk;
                        pk.x = pk2(fmaxf(acc[cc][nt][0] + bi.x, 0.f), fmaxf(acc[cc][nt][1] + bi.y, 0.f));
                        pk.y = pk2(fmaxf(acc[cc][nt][2] + bi.z, 0.f), fmaxf(acc[cc][nt][3] + bi.w, 0.f));
                        *(int2*)&z1[node * LDH + o0] = pk;
                    }
                }
            }
            __syncthreads();
            {
                f32x4 acc[2] = {};
#pragma unroll
                for (int ks = 0; ks < 4; ++ks) {
                    bf16x8 b0 = *(bf16x8*)&z1[lr * LDH + 32 * ks + 8 * lk];
                    bf16x8 b1 = *(bf16x8*)&z1[(16 + lr) * LDH + 32 * ks + 8 * lk];
                    acc[0] = __builtin_amdgcn_mfma_f32_16x16x32_bf16(A2[ks], b0, acc[0], 0, 0, 0);
                    acc[1] = __builtin_amdgcn_mfma_f32_16x16x32_bf16(A2[ks], b1, acc[1], 0, 0, 0);
                }
                int o0 = 16 * w + 4 * lk;
                float4 bi = *(const float4*)&b2f[k * 64 + o0];
#pragma unroll
                for (int nt = 0; nt < 2; ++nt) {
                    int node = nt * 16 + lr;
                    int2 pk;
                    pk.x = pk2(fmaxf(acc[nt][0] + bi.x, 0.f), fmaxf(acc[nt][1] + bi.y, 0.f));
                    pk.y = pk2(fmaxf(acc[nt][2] + bi.z, 0.f), fmaxf(acc[nt][3] + bi.w, 0.f));
                    *(int2*)&z2[node * LDZ + o0] = pk;
                }
            }
            __syncthreads();
            {
                f32x4 acc = {};
#pragma unroll
                for (int ks = 0; ks < 2; ++ks) {
                    bf16x8 b = *(bf16x8*)&z2[(16 * rh + lr) * LDZ + 32 * ks + 8 * lk];
                    acc = __builtin_amdgcn_mfma_f32_16x16x32_bf16(A3[ks], b, acc, 0, 0, 0);
                }
                int o0 = 16 * ch + 4 * lk;
                if (o0 < 24) {
                    int n = n0 + 16 * rh + lr;
                    float b0 = b3f[k * 24 + o0], b1 = b3f[k * 24 + o0 + 1];
                    float b2v = b3f[k * 24 + o0 + 2], b3v = b3f[k * 24 + o0 + 3];
                    float2 s0, s1;
                    s0.x = fsig(acc[0] + b0);
                    s0.y = fsig(acc[1] + b1);
                    s1.x = fsig(acc[2] + b2v);
                    s1.y = fsig(acc[3] + b3v);
                    size_t base = (size_t)n * OUT_F + 6 + 24 * k + o0;
                    *(float2*)&out[base] = s0;
                    *(float2*)&out[base + 2] = s1;
                }
            }
        }
    } else {
        bf16x8 C1[4], C2[2];
#pragma unroll
        for (int ks = 0; ks < 4; ++ks)
            C1[ks] = *(const bf16x8*)&cntW1t[(16 * w + lr) * 128 + 32 * ks + 8 * lk];
#pragma unroll
        for (int ks = 0; ks < 2; ++ks)
            C2[ks] = *(const bf16x8*)&cntW2ft[lr * 64 + 32 * ks + 8 * lk];

        for (int tile = bx; tile < 3125; tile += HEAD_BX) {
            int n0 = tile * 32;
#pragma unroll
            for (int it = 0; it < 2; ++it) {
                int idx = (t + it * 256) * 8;
                int r = idx >> 7, c = idx & 127;
                *(int4*)&hs[r * LDH + c] = *(const int4*)&hb[(size_t)(n0 + r) * 128 + c];
            }
            __syncthreads();
            {
                f32x4 acc[2] = {};
#pragma unroll
                for (int ks = 0; ks < 4; ++ks) {
                    bf16x8 b0 = *(bf16x8*)&hs[lr * LDH + 32 * ks + 8 * lk];
                    bf16x8 b1 = *(bf16x8*)&hs[(16 + lr) * LDH + 32 * ks + 8 * lk];
                    acc[0] = __builtin_amdgcn_mfma_f32_16x16x32_bf16(C1[ks], b0, acc[0], 0, 0, 0);
                    acc[1] = __builtin_amdgcn_mfma_f32_16x16x32_bf16(C1[ks], b1, acc[1], 0, 0, 0);
                }
                int o0 = 16 * w + 4 * lk;
                float4 bi = *(const float4*)&cntb1[o0];
#pragma unroll
                for (int nt = 0; nt < 2; ++nt) {
                    int node = nt * 16 + lr;
                    int2 pk;
                    pk.x = pk2(fmaxf(acc[nt][0] + bi.x, 0.f), fmaxf(acc[nt][1] + bi.y, 0.f));
                    pk.y = pk2(fmaxf(acc[nt][2] + bi.z, 0.f), fmaxf(acc[nt][3] + bi.w, 0.f));
                    *(int2*)&z2[node * LDZ + o0] = pk;
                }
            }
            __syncthreads();
            if (w < 2) {
                f32x4 acc = {};
#pragma unroll
                for (int ks = 0; ks < 2; ++ks) {
                    bf16x8 b = *(bf16x8*)&z2[(16 * w + lr) * LDZ + 32 * ks + 8 * lk];
                    acc = __builtin_amdgcn_mfma_f32_16x16x32_bf16(C2[ks], b, acc, 0, 0, 0);
                }
                int n = n0 + 16 * w + lr;
#pragma unroll
                for (int j = 0; j < 4; ++j) {
                    int o = 4 * lk + j;
                    if (o < 6) out[(size_t)n * OUT_F + o] = acc[j] + cntb2f[o];
                }
            }
            __syncthreads();
        }
    }
}

extern "C" void kernel_launch(void* const* d_in, const int* in_sizes, int n_in,
                              void* d_out, int out_size, void* d_ws, size_t ws_size,
                              hipStream_t stream) {
    const float* x = (const float*)d_in[0];
    const int* ei = (const int*)d_in[1];
    const float* W1l = (const float*)d_in[2];
    const float* W1r = (const float*)d_in[3];
    const float* b1 = (const float*)d_in[4];
    const float* bn1_g = (const float*)d_in[5];
    const float* bn1_b = (const float*)d_in[6];
    const float* bn1_m = (const float*)d_in[7];
    const float* bn1_v = (const float*)d_in[8];
    const float* W2l = (const float*)d_in[9];
    const float* W2r = (const float*)d_in[10];
    const float* b2 = (const float*)d_in[11];
    const float* bn2_g = (const float*)d_in[12];
    const float* bn2_b = (const float*)d_in[13];
    const float* bn2_m = (const float*)d_in[14];
    const float* bn2_v = (const float*)d_in[15];
    const float* cnt_W1 = (const float*)d_in[16];
    const float* cnt_b1 = (const float*)d_in[17];
    const float* cnt_bn_g = (const float*)d_in[18];
    const float* cnt_bn_b = (const float*)d_in[19];
    const float* cnt_bn_m = (const float*)d_in[20];
    const float* cnt_bn_v = (const float*)d_in[21];
    const float* cnt_W2 = (const float*)d_in[22];
    const float* cnt_b2 = (const float*)d_in[23];
    const float* ch_W1 = (const float*)d_in[24];
    const float* ch_b1 = (const float*)d_in[25];
    const float* ch_bn1_g = (const float*)d_in[26];
    const float* ch_bn1_b = (const float*)d_in[27];
    const float* ch_bn1_m = (const float*)d_in[28];
    const float* ch_bn1_v = (const float*)d_in[29];
    const float* ch_W2 = (const float*)d_in[30];
    const float* ch_b2 = (const float*)d_in[31];
    const float* ch_bn2_g = (const float*)d_in[32];
    const float* ch_bn2_b = (const float*)d_in[33];
    const float* ch_bn2_m = (const float*)d_in[34];
    const float* ch_bn2_v = (const float*)d_in[35];
    const float* ch_W3 = (const float*)d_in[36];
    const float* ch_b3 = (const float*)d_in[37];

    float* out = (float*)d_out;

    int* cnt = (int*)d_ws;
    int* dbins = cnt + N_NODES;
    int* bcur = dbins + 64;
    int* dcur = bcur + 256;
    int* rowstart = dcur + 64;
    int* cursor = rowstart + N_NODES;
    int* blocksums = cursor + N_NODES;
    int* perm = blocksums + 512;
    int* sorted_src = perm + N_NODES;
    int2* bucketed = (int2*)(sorted_src + N_EDGES);
    unsigned char* h1f8 = (unsigned char*)bucketed;  // aliased; bucketed dead after fill2
    short* h1b = (short*)(bucketed + (size_t)NBUCK * BCAP);
    short* hb = h1b + (size_t)N_NODES * H;
    short* W1t = hb + (size_t)N_NODES * H;
    short* W2ft = W1t + 98304;
    short* W3ft = W2ft + 49152;
    short* cntW1t = W3ft + 12288;
    short* cntW2ft = cntW1t + 8192;
    short* W2t = cntW2ft + 1024;
    float* b2f = (float*)(W2t + 32768);
    float* b3f = b2f + 384;
    float* cntb2f = b3f + 144;

    hipMemsetAsync(dbins, 0, (64 + 256) * sizeof(int), stream);

    k_prep<<<791, 256, 0, stream>>>(ch_W1, ch_W2, ch_W3,
                                    ch_bn1_g, ch_bn1_b, ch_bn1_m, ch_bn1_v,
                                    ch_bn2_g, ch_bn2_b, ch_bn2_m, ch_bn2_v,
                                    cnt_W1, cnt_W2,
                                    cnt_bn_g, cnt_bn_b, cnt_bn_m, cnt_bn_v,
                                    ch_b2, ch_b3, cnt_b2, W2l, W2r,
                                    W1t, W2ft, W3ft, cntW1t, cntW2ft, W2t,
                                    b2f, b3f, cntb2f);

    k_bucket<<<391, 256, 0, stream>>>(ei, bcur, bucketed);
    k_hist2<<<NBUCK, 256, 0, stream>>>(bucketed, bcur, cnt);
    k_scan1<<<SCAN_BLOCKS, 256, 0, stream>>>(cnt, rowstart, blocksums);
    k_scan2<<<1, 512, 0, stream>>>(blocksums);
    k_scan3<<<SCAN_BLOCKS, 256, 0, stream>>>(rowstart, blocksums, cursor);
    k_fill2<<<NBUCK * 40, 256, 0, stream>>>(bucketed, bcur, cursor, sorted_src);

    k_deghist<<<SCAN_BLOCKS, 256, 0, stream>>>(cnt, dbins);
    k_degscan<<<1, 64, 0, stream>>>(dbins, dcur);
    k_degscatter<<<SCAN_BLOCKS, 256, 0, stream>>>(cnt, dcur, perm);

    k_agg1_layer1<<<N_NODES / 16, 256, 0, stream>>>(x, rowstart, cnt, sorted_src, perm,
                                                    W1l, W1r, b1,
                                                    bn1_g, bn1_b, bn1_m, bn1_v, h1b, h1f8);
    k_agg2_layer2<<<N_NODES / 32, 256, 0, stream>>>(h1b, h1f8, rowstart, cnt, sorted_src, perm,
                                                    W2t, b2,
                                                    bn2_g, bn2_b, bn2_m, bn2_v, hb);
    k_heads_mfma<<<dim3(HEAD_BX, 7), 256, 0, stream>>>(
        hb, cnt_b1, ch_b1, W1t, W2ft, W3ft, cntW1t, cntW2ft,
        b2f, b3f, cntb2f, out);
}